// Round 4
// baseline (201.852 us; speedup 1.0000x reference)
//
#include <hip/hip_runtime.h>
#include <hip/hip_bf16.h>

constexpr int Bt  = 131072;
constexpr int OBS = 194;
constexpr int Hd  = 64;
constexpr int NT  = 256;   // 4 waves / block
constexpr int MT  = 64;    // rows per block (16 per wave)
constexpr int HS  = 72;    // h-buffer row stride (shorts): 16B-aligned + bank-stagger
constexpr int LS  = 18;    // logit buffer row stride

// d_ws layout (shorts): B-fragment layouts for mfma_f32_16x16x32_bf16.
// frag_base[(kb*NTILES + nt)*64 + lane], 8 shorts each;
// value j of lane l = W[k = kb*32 + (l>>4)*8 + j][n = nt*16 + (l&15)], zero-padded k>=194.
constexpr int W1B_OFF  = 0;       // 7*4*64*8 = 28672
constexpr int WC1B_OFF = 28672;
constexpr int W2B_OFF  = 57344;   // 2*4*64*8 = 8192
constexpr int WC2B_OFF = 65536;
constexpr int WHB_OFF  = 73728;   // 2*1*64*8 = 1024 (cols 0-14: Wh, col 15: Wc3)

typedef short bf8   __attribute__((ext_vector_type(8)));
typedef float f32x4 __attribute__((ext_vector_type(4)));

__device__ __forceinline__ short f2bs(float f) {
    union { __hip_bfloat16 h; short s; } u;
    u.h = __float2bfloat16(f);
    return u.s;
}
__device__ __forceinline__ float bs2f(short s) {
    union { short s; __hip_bfloat16 h; } u;
    u.s = s;
    return __bfloat162float(u.h);
}
__device__ __forceinline__ float fast_tanh(float v) {
    v = fminf(fmaxf(v, -15.f), 15.f);
    float e = __expf(2.f * v);
    return (e - 1.f) * __builtin_amdgcn_rcpf(e + 1.f);
}

// ---------------- prep: convert weights -> B-fragment layout in d_ws ----------------
__global__ void __launch_bounds__(256) prep(
    const float* __restrict__ W1, const float* __restrict__ W2,
    const float* __restrict__ Wh, const float* __restrict__ Wc1,
    const float* __restrict__ Wc2, const float* __restrict__ Wc3,
    short* __restrict__ ws)
{
    const int gid = blockIdx.x * 256 + threadIdx.x;
    const int gsz = gridDim.x * 256;

    for (int i = gid; i < 28672; i += gsz) {
        int j = i & 7, l = (i >> 3) & 63, nt = (i >> 9) & 3, kb = i >> 11;
        int k = kb * 32 + ((l >> 4) << 3) + j;
        int n = nt * 16 + (l & 15);
        short v1 = 0, v2 = 0;
        if (k < OBS) {
            v1 = f2bs(W1[k * 64 + n]);
            v2 = f2bs(Wc1[k * 64 + n]);
        }
        ws[W1B_OFF + i]  = v1;
        ws[WC1B_OFF + i] = v2;
    }
    for (int i = gid; i < 8192; i += gsz) {
        int j = i & 7, l = (i >> 3) & 63, nt = (i >> 9) & 3, kb = i >> 11;
        int k = kb * 32 + ((l >> 4) << 3) + j;
        int n = nt * 16 + (l & 15);
        ws[W2B_OFF + i]  = f2bs(W2[k * 64 + n]);
        ws[WC2B_OFF + i] = f2bs(Wc2[k * 64 + n]);
    }
    for (int i = gid; i < 1024; i += gsz) {
        int j = i & 7, l = (i >> 3) & 63, kb = i >> 9;
        int k = kb * 32 + ((l >> 4) << 3) + j;
        int cc = l & 15;
        float v;
        if (cc == 15) v = Wc3[k];
        else { int e = cc / 5, a = cc - 5 * e; v = Wh[(e * 64 + k) * 5 + a]; }
        ws[WHB_OFF + i] = f2bs(v);
    }
}

// ------------- main fused kernel: actor+critic layer-fused, no barriers -------------
__global__ void __launch_bounds__(NT, 4) fused_ac(
    const float* __restrict__ x, const int* __restrict__ act_in,
    const float* __restrict__ b1, const float* __restrict__ b2,
    const float* __restrict__ bh, const float* __restrict__ bc1,
    const float* __restrict__ bc2, const float* __restrict__ bc3,
    const short* __restrict__ ws,
    float* __restrict__ out)
{
    __shared__ __align__(16) short hA[4][16 * HS];   // per-wave actor h/feat (A-layout)
    __shared__ __align__(16) short hC[4][16 * HS];   // per-wave critic h/feat
    __shared__ short logitb[4][16 * LS];
    __shared__ float valb[4][16];
    // 9216 + 9216 + 2304 + 256 = 20992 B -> ~7 blocks/CU LDS-wise

    const int t  = threadIdx.x;
    const int w  = t >> 6;
    const int l  = t & 63;
    const int q  = l >> 4;
    const int c  = l & 15;
    const int b0 = blockIdx.x * MT;

    const bf8* __restrict__ fW1  = reinterpret_cast<const bf8*>(ws + W1B_OFF);
    const bf8* __restrict__ fWc1 = reinterpret_cast<const bf8*>(ws + WC1B_OFF);
    const bf8* __restrict__ fW2  = reinterpret_cast<const bf8*>(ws + W2B_OFF);
    const bf8* __restrict__ fWc2 = reinterpret_cast<const bf8*>(ws + WC2B_OFF);
    const bf8* __restrict__ fWh  = reinterpret_cast<const bf8*>(ws + WHB_OFF);

    short* ha = hA[w];
    short* hc = hC[w];

    // ---------------- layer 1 (actor + critic share each x fragment) ----------------
    f32x4 aa[4], ac[4];
    #pragma unroll
    for (int nt = 0; nt < 4; ++nt) {
        aa[nt] = f32x4{0.f, 0.f, 0.f, 0.f};
        ac[nt] = f32x4{0.f, 0.f, 0.f, 0.f};
    }
    {
        const float* xr = x + (size_t)(b0 + w * 16 + c) * OBS;
        #pragma unroll
        for (int kb = 0; kb < 6; ++kb) {
            const float2* p = reinterpret_cast<const float2*>(xr + kb * 32 + q * 8);
            float2 v0 = p[0], v1 = p[1], v2 = p[2], v3 = p[3];
            bf8 a;
            a[0] = f2bs(v0.x); a[1] = f2bs(v0.y); a[2] = f2bs(v1.x); a[3] = f2bs(v1.y);
            a[4] = f2bs(v2.x); a[5] = f2bs(v2.y); a[6] = f2bs(v3.x); a[7] = f2bs(v3.y);
            #pragma unroll
            for (int nt = 0; nt < 4; ++nt) {
                aa[nt] = __builtin_amdgcn_mfma_f32_16x16x32_bf16(a, fW1 [(kb * 4 + nt) * 64 + l], aa[nt], 0, 0, 0);
                ac[nt] = __builtin_amdgcn_mfma_f32_16x16x32_bf16(a, fWc1[(kb * 4 + nt) * 64 + l], ac[nt], 0, 0, 0);
            }
        }
        bf8 a6 = {0, 0, 0, 0, 0, 0, 0, 0};
        if (q == 0) {                           // k = 192,193 (B zero-padded past 194)
            float2 v = *reinterpret_cast<const float2*>(xr + 192);
            a6[0] = f2bs(v.x); a6[1] = f2bs(v.y);
        }
        #pragma unroll
        for (int nt = 0; nt < 4; ++nt) {
            aa[nt] = __builtin_amdgcn_mfma_f32_16x16x32_bf16(a6, fW1 [(6 * 4 + nt) * 64 + l], aa[nt], 0, 0, 0);
            ac[nt] = __builtin_amdgcn_mfma_f32_16x16x32_bf16(a6, fWc1[(6 * 4 + nt) * 64 + l], ac[nt], 0, 0, 0);
        }
    }
    // D layout: lane holds D[row = q*4+r][col = nt*16+c] -> tanh -> LDS (A-layout)
    #pragma unroll
    for (int nt = 0; nt < 4; ++nt) {
        float ba = b1[nt * 16 + c], bc = bc1[nt * 16 + c];
        #pragma unroll
        for (int r = 0; r < 4; ++r) {
            ha[(q * 4 + r) * HS + nt * 16 + c] = f2bs(fast_tanh(aa[nt][r] + ba));
            hc[(q * 4 + r) * HS + nt * 16 + c] = f2bs(fast_tanh(ac[nt][r] + bc));
        }
    }

    // ---------------- layer 2 ----------------
    #pragma unroll
    for (int nt = 0; nt < 4; ++nt) {
        aa[nt] = f32x4{0.f, 0.f, 0.f, 0.f};
        ac[nt] = f32x4{0.f, 0.f, 0.f, 0.f};
    }
    #pragma unroll
    for (int kb = 0; kb < 2; ++kb) {
        bf8 xa = *reinterpret_cast<const bf8*>(&ha[c * HS + kb * 32 + q * 8]);
        bf8 xc = *reinterpret_cast<const bf8*>(&hc[c * HS + kb * 32 + q * 8]);
        #pragma unroll
        for (int nt = 0; nt < 4; ++nt) {
            aa[nt] = __builtin_amdgcn_mfma_f32_16x16x32_bf16(xa, fW2 [(kb * 4 + nt) * 64 + l], aa[nt], 0, 0, 0);
            ac[nt] = __builtin_amdgcn_mfma_f32_16x16x32_bf16(xc, fWc2[(kb * 4 + nt) * 64 + l], ac[nt], 0, 0, 0);
        }
    }
    #pragma unroll
    for (int nt = 0; nt < 4; ++nt) {
        float ba = b2[nt * 16 + c], bc = bc2[nt * 16 + c];
        #pragma unroll
        for (int r = 0; r < 4; ++r) {
            ha[(q * 4 + r) * HS + nt * 16 + c] = f2bs(fast_tanh(aa[nt][r] + ba));
            hc[(q * 4 + r) * HS + nt * 16 + c] = f2bs(fast_tanh(ac[nt][r] + bc));
        }
    }

    // -------- head: feat[16x64] @ WhB[64x16] (cols 0-14 logits / col 15 value) --------
    {
        f32x4 lg = f32x4{0.f, 0.f, 0.f, 0.f};
        f32x4 vv = f32x4{0.f, 0.f, 0.f, 0.f};
        #pragma unroll
        for (int kb = 0; kb < 2; ++kb) {
            bf8 bw = fWh[kb * 64 + l];
            bf8 fa = *reinterpret_cast<const bf8*>(&ha[c * HS + kb * 32 + q * 8]);
            bf8 fc = *reinterpret_cast<const bf8*>(&hc[c * HS + kb * 32 + q * 8]);
            lg = __builtin_amdgcn_mfma_f32_16x16x32_bf16(fa, bw, lg, 0, 0, 0);
            vv = __builtin_amdgcn_mfma_f32_16x16x32_bf16(fc, bw, vv, 0, 0, 0);
        }
        short* lw = logitb[w];
        #pragma unroll
        for (int r = 0; r < 4; ++r)
            lw[(q * 4 + r) * LS + c] = f2bs(lg[r]);
        if (c == 15) {
            float bc3v = bc3[0];
            #pragma unroll
            for (int r = 0; r < 4; ++r)
                valb[w][q * 4 + r] = vv[r] + bc3v;
        }
    }

    // ---------------- per-row softmax epilogue (quads redundant over m) ----------------
    {
        int m  = c;
        int gm = b0 + w * 16 + m;
        const float* xr = x + (size_t)gm * OBS;
        float x0 = xr[0], x1 = xr[1], x2 = xr[2];
        int ev = 0; float best = x0;
        if (x1 > best) { best = x1; ev = 1; }
        if (x2 > best) { ev = 2; }
        const short* lw = logitb[w];
        float lg[5];
        #pragma unroll
        for (int a = 0; a < 5; ++a)
            lg[a] = bs2f(lw[m * LS + ev * 5 + a]) + bh[ev * 5 + a];
        float mx = lg[0];
        #pragma unroll
        for (int a = 1; a < 5; ++a) mx = fmaxf(mx, lg[a]);
        float se = 0.f;
        #pragma unroll
        for (int a = 0; a < 5; ++a) se += __expf(lg[a] - mx);
        float lse = __logf(se) + mx;
        int act = act_in[gm];
        float lsel = lg[0];
        #pragma unroll
        for (int a = 1; a < 5; ++a) lsel = (act == a) ? lg[a] : lsel;
        float ent = 0.f;
        #pragma unroll
        for (int a = 0; a < 5; ++a) { float lp = lg[a] - lse; ent -= __expf(lp) * lp; }

        if (l < 16) {
            out[gm]          = (float)act;
            out[Bt + gm]     = lsel - lse;
            out[2 * Bt + gm] = ent;
            out[3 * Bt + gm] = valb[w][m];
        }
    }
}

extern "C" void kernel_launch(void* const* d_in, const int* in_sizes, int n_in,
                              void* d_out, int out_size, void* d_ws, size_t ws_size,
                              hipStream_t stream) {
    const float* x   = (const float*)d_in[0];
    const int*   act = (const int*)  d_in[1];
    const float* W1  = (const float*)d_in[2];
    const float* b1  = (const float*)d_in[3];
    const float* W2  = (const float*)d_in[4];
    const float* b2  = (const float*)d_in[5];
    const float* Wh  = (const float*)d_in[6];
    const float* bh  = (const float*)d_in[7];
    const float* Wc1 = (const float*)d_in[8];
    const float* bc1 = (const float*)d_in[9];
    const float* Wc2 = (const float*)d_in[10];
    const float* bc2 = (const float*)d_in[11];
    const float* Wc3 = (const float*)d_in[12];
    const float* bc3 = (const float*)d_in[13];
    float* out = (float*)d_out;
    short* ws  = (short*)d_ws;

    hipLaunchKernelGGL(prep, dim3(64), dim3(256), 0, stream,
                       W1, W2, Wh, Wc1, Wc2, Wc3, ws);
    hipLaunchKernelGGL(fused_ac, dim3(Bt / MT), dim3(NT), 0, stream,
                       x, act, b1, b2, bh, bc1, bc2, bc3, ws, out);
}